// Round 4
// baseline (280.756 us; speedup 1.0000x reference)
//
#include <hip/hip_runtime.h>
#include <hip/hip_bf16.h>

#define B_ 64
#define S_ 1024
#define H_ 1024
#define M_ (B_*S_)   // 65536 rows of the big GEMM

typedef __attribute__((ext_vector_type(8))) short short8;
typedef __attribute__((ext_vector_type(4))) float f32x4;

__device__ __forceinline__ unsigned short f2bf(float f) {
    union { float f; unsigned u; } c; c.f = f;
    unsigned u = c.u;
    unsigned r = (u + 0x7fffu + ((u >> 16) & 1u)) >> 16;  // RTNE, finite inputs
    return (unsigned short)r;
}

__device__ __forceinline__ float bf2f(unsigned short h) {
    union { unsigned u; float f; } c; c.u = ((unsigned)h) << 16;
    return c.f;
}

__device__ __forceinline__ float tanh_fast(float x) {
    float t = __expf(2.0f * x);
    return 1.0f - 2.0f * __builtin_amdgcn_rcpf(t + 1.0f);  // inf-safe
}

// async global->LDS, 16B per lane. LDS dest = wave-uniform base + lane*16.
__device__ __forceinline__ void gll16(const unsigned short* g, unsigned short* l) {
    auto* gp = (const __attribute__((address_space(1))) unsigned short*)(g);
    auto* lp = (__attribute__((address_space(3))) unsigned short*)(l);
    __builtin_amdgcn_global_load_lds(gp, lp, 16, 0, 0);
}

// ---------------------------------------------------------------------------
// K0: f32 -> bf16 conversion (8 elems/thread/iter, 16B stores)
// ---------------------------------------------------------------------------
__global__ void cvt_bf16_kernel(const float* __restrict__ src,
                                unsigned short* __restrict__ dst, int n8) {
    int idx = blockIdx.x * blockDim.x + threadIdx.x;
    int stride = gridDim.x * blockDim.x;
    for (int i = idx; i < n8; i += stride) {
        const float4* s4 = (const float4*)src + (size_t)i * 2;
        float4 a = s4[0], b = s4[1];
        short8 o;
        o[0] = f2bf(a.x); o[1] = f2bf(a.y); o[2] = f2bf(a.z); o[3] = f2bf(a.w);
        o[4] = f2bf(b.x); o[5] = f2bf(b.y); o[6] = f2bf(b.z); o[7] = f2bf(b.w);
        *((short8*)dst + i) = o;
    }
}

// ---------------------------------------------------------------------------
// K1a: proj_s split-K partials. grid = 256 = (kt 16) x (hs 16), 256 thr.
// ---------------------------------------------------------------------------
__global__ void proj_s_part_kernel(const float* __restrict__ dec,
                                   const float* __restrict__ Ws,
                                   float* __restrict__ part) {
    __shared__ float wss[64][68];
    const int kt = blockIdx.x & 15, hs = blockIdx.x >> 4;
    const int k0 = kt * 64, h0 = hs * 64;
    const int t = threadIdx.x;

    {
        const int r = t >> 2, c = (t & 3) * 16;
        const float4* src = (const float4*)(Ws + (size_t)(k0 + r) * H_ + h0 + c);
        float4 v0 = src[0], v1 = src[1], v2 = src[2], v3 = src[3];
        *(float4*)&wss[r][c + 0]  = v0;
        *(float4*)&wss[r][c + 4]  = v1;
        *(float4*)&wss[r][c + 8]  = v2;
        *(float4*)&wss[r][c + 12] = v3;
    }
    const int b = t >> 2, kq = t & 3;
    float4 dreg[16];
    const float4* dsrc = (const float4*)(dec + (size_t)b * H_ + h0);
#pragma unroll
    for (int i = 0; i < 16; ++i) dreg[i] = dsrc[i];
    __syncthreads();

    float acc[16] = {};
#pragma unroll
    for (int h4 = 0; h4 < 16; ++h4) {
        float4 d = dreg[h4];
#pragma unroll
        for (int j = 0; j < 16; ++j) {
            float4 wv = *(const float4*)&wss[kq + 4 * j][h4 * 4];
            acc[j] = fmaf(d.x, wv.x, acc[j]);
            acc[j] = fmaf(d.y, wv.y, acc[j]);
            acc[j] = fmaf(d.z, wv.z, acc[j]);
            acc[j] = fmaf(d.w, wv.w, acc[j]);
        }
    }
#pragma unroll
    for (int j = 0; j < 16; ++j)
        part[(size_t)hs * M_ + b * H_ + k0 + kq + 4 * j] = acc[j];
}

__global__ void proj_red_kernel(const float* __restrict__ part,
                                float* __restrict__ proj_s) {
    int i = blockIdx.x * 256 + threadIdx.x;
    float s = 0.0f;
#pragma unroll
    for (int p = 0; p < 16; ++p) s += part[(size_t)p * M_ + i];
    proj_s[i] = s;
}

// ---------------------------------------------------------------------------
// K2: 256x256 tile, BK=32, 8 waves, dbuf LDS, counted vmcnt(3) pipeline,
// XOR-swizzled LDS, raw s_barrier, setprio around MFMA. Fused tanh+v-dot.
//
// Staging protocol (prefetch lead = 3 half-tiles, provably race-free):
//   boundary of tile t-1: stage {A0,A1,B0} of tile t+1  (buffer freed there)
//   phase 0   of tile t  : stage {B1} of tile t+1
//   boundary wait: s_waitcnt vmcnt(3)  -> tile t+1 complete, trio of t+2 flies
// ---------------------------------------------------------------------------
__global__ void __launch_bounds__(512)
fused_scores_8p_kernel(const unsigned short* __restrict__ encb,
                       const unsigned short* __restrict__ Whb,
                       const float* __restrict__ proj_s,
                       const float* __restrict__ v,
                       float* __restrict__ scores_part) {
    __shared__ __align__(16) unsigned short Lsh[32768];  // 64KB: 2 buf x (A 16KB + B 16KB)

    // XCD swizzle: 1024 blocks, 8 XCDs -> each XCD gets 128 consecutive
    const int bx0 = blockIdx.x;
    const int bx = (bx0 & 7) * 128 + (bx0 >> 3);
    const int nt = bx & 3;    // 4 N-tiles of 256
    const int mt = bx >> 2;   // 256 M-tiles of 256
    const int t = threadIdx.x;
    const int wid = t >> 6, lane = t & 63;
    const int wr = wid >> 2, wc = wid & 3;       // 2M x 4N wave grid
    const int lrow = lane & 15, lgrp = lane >> 4;

    f32x4 acc[8][4] = {};

    // ---- staging addresses (pre-swizzled global source, linear LDS dest) ----
    const int srow = t >> 2;                            // 0..127
    const int scol = ((t & 3) ^ ((t >> 3) & 3)) * 8;    // swizzled halfword col
    const unsigned short* gA = encb + (size_t)(mt * 256 + srow) * H_ + scol;
    const unsigned short* gB = Whb  + (size_t)(nt * 256 + srow) * H_ + scol;
    unsigned short* lws = Lsh + wid * 512;              // wave-uniform LDS base (hw)

    // op: 0=A, 1=B ; h: half (128 rows) ; kt: K-tile index
    #define STAGE(c, op, h, kt) \
        gll16(((op) ? gB : gA) + (size_t)(h) * (128 * H_) + (kt) * 32, \
              lws + (c) * 16384 + (op) * 8192 + (h) * 4096)

    // ---- fragment read offsets (byte, swizzle matches stage) ----
    int aoff[8], boff[4];
#pragma unroll
    for (int m = 0; m < 8; ++m) {
        int row = wr * 128 + m * 16 + lrow;
        aoff[m] = row * 64 + ((lgrp ^ ((row >> 1) & 3)) * 16);
    }
#pragma unroll
    for (int n = 0; n < 4; ++n) {
        int row = wc * 64 + n * 16 + lrow;
        boff[n] = row * 64 + ((lgrp ^ ((row >> 1) & 3)) * 16);
    }

    // ---- prologue: tile0 full + tile1 trio; wait tile0, keep trio in flight
    STAGE(0, 0, 0, 0); STAGE(0, 0, 1, 0); STAGE(0, 1, 0, 0); STAGE(0, 1, 1, 0);
    STAGE(1, 0, 0, 1); STAGE(1, 0, 1, 1); STAGE(1, 1, 0, 1);
    asm volatile("s_waitcnt vmcnt(3)" ::: "memory");
    __builtin_amdgcn_sched_barrier(0);
    __builtin_amdgcn_s_barrier();

    int cur = 0;
    for (int kt = 0; kt < 32; ++kt) {
#pragma unroll
        for (int p = 0; p < 4; ++p) {
            const int qm = p >> 1, qn = p & 1;
            short8 af[4], bfr[2];
#pragma unroll
            for (int mm = 0; mm < 4; ++mm)
                af[mm] = *(const short8*)((const char*)Lsh + cur * 32768 + aoff[qm * 4 + mm]);
#pragma unroll
            for (int nn = 0; nn < 2; ++nn)
                bfr[nn] = *(const short8*)((const char*)Lsh + cur * 32768 + 16384 + boff[qn * 2 + nn]);
            if (p == 0 && kt + 1 < 32) { STAGE(cur ^ 1, 1, 1, kt + 1); }  // B1 of next
            __builtin_amdgcn_s_barrier();
            __builtin_amdgcn_s_setprio(1);
#pragma unroll
            for (int mm = 0; mm < 4; ++mm)
#pragma unroll
                for (int nn = 0; nn < 2; ++nn)
                    acc[qm * 4 + mm][qn * 2 + nn] =
                        __builtin_amdgcn_mfma_f32_16x16x32_bf16(af[mm], bfr[nn],
                            acc[qm * 4 + mm][qn * 2 + nn], 0, 0, 0);
            __builtin_amdgcn_s_setprio(0);
            __builtin_amdgcn_s_barrier();
        }
        if (kt + 2 < 32) {   // buffer cur freed by the phase-3 post-barrier
            STAGE(cur, 0, 0, kt + 2);
            STAGE(cur, 0, 1, kt + 2);
            STAGE(cur, 1, 0, kt + 2);
        }
        asm volatile("s_waitcnt vmcnt(3)" ::: "memory");
        __builtin_amdgcn_sched_barrier(0);
        __builtin_amdgcn_s_barrier();
        cur ^= 1;
    }
    #undef STAGE

    // ---- epilogue: tanh(acc + proj_s) . v, reduce over cols ----
    const int b = mt >> 2;   // 4 M-tiles per batch row (256 | 1024)
    float vv[4], ps[4];
#pragma unroll
    for (int n = 0; n < 4; ++n) {
        int col = nt * 256 + wc * 64 + n * 16 + lrow;
        vv[n] = v[col];
        ps[n] = proj_s[b * H_ + col];
    }
    float* sums = (float*)Lsh;   // reuse: [256 rows][4 wc] f32 = 4KB
#pragma unroll
    for (int m = 0; m < 8; ++m) {
#pragma unroll
        for (int j = 0; j < 4; ++j) {
            float s = 0.0f;
#pragma unroll
            for (int n = 0; n < 4; ++n)
                s = fmaf(tanh_fast(acc[m][n][j] + ps[n]), vv[n], s);
            s += __shfl_xor(s, 1, 64);
            s += __shfl_xor(s, 2, 64);
            s += __shfl_xor(s, 4, 64);
            s += __shfl_xor(s, 8, 64);
            if (lrow == 0)
                sums[(wr * 128 + m * 16 + lgrp * 4 + j) * 4 + wc] = s;
        }
    }
    __syncthreads();
    if (t < 256) {
        float r = sums[t * 4 + 0] + sums[t * 4 + 1] + sums[t * 4 + 2] + sums[t * 4 + 3];
        scores_part[(size_t)nt * M_ + mt * 256 + t] = r;
    }
}

// ---------------------------------------------------------------------------
// K2 fallback: f32-input version (reg-staged conversion), 128x128, np=8.
// ---------------------------------------------------------------------------
__global__ void fused_scores_kernel(const float* __restrict__ enc,
                                    const float* __restrict__ Wh,
                                    const float* __restrict__ proj_s,
                                    const float* __restrict__ v,
                                    float* __restrict__ scores_part) {
    __shared__ __align__(16) unsigned short As[128][40];
    __shared__ __align__(16) unsigned short Bs[128][40];
    __shared__ float sums[128][2];

    const int bx = blockIdx.x;
    const int nt = bx & 7;
    const int mt = bx >> 3;
    const int t = threadIdx.x;
    const int w = t >> 6, lane = t & 63;
    const int wr = w >> 1, wc = w & 1;
    const int lrow = lane & 15, lgrp = lane >> 4;

    f32x4 acc[4][4] = {};

    const int srow = t >> 1;
    const int shalf = t & 1;
    const float* gA = enc + (size_t)(mt * 128 + srow) * H_ + shalf * 16;
    const float* gB = Wh  + (size_t)(nt * 128 + srow) * H_ + shalf * 16;
    unsigned short* lA = &As[srow][shalf * 16];
    unsigned short* lB = &Bs[srow][shalf * 16];

    for (int kt = 0; kt < H_ / 32; ++kt) {
        __syncthreads();
        const float4* a4 = (const float4*)(gA + kt * 32);
        const float4* b4 = (const float4*)(gB + kt * 32);
        union { unsigned short us[16]; uint4 q[2]; } pa, pb;
#pragma unroll
        for (int i = 0; i < 4; ++i) {
            float4 av = a4[i];
            float4 bv = b4[i];
            pa.us[i*4+0] = f2bf(av.x); pa.us[i*4+1] = f2bf(av.y);
            pa.us[i*4+2] = f2bf(av.z); pa.us[i*4+3] = f2bf(av.w);
            pb.us[i*4+0] = f2bf(bv.x); pb.us[i*4+1] = f2bf(bv.y);
            pb.us[i*4+2] = f2bf(bv.z); pb.us[i*4+3] = f2bf(bv.w);
        }
        *(uint4*)(lA)     = pa.q[0];
        *(uint4*)(lA + 8) = pa.q[1];
        *(uint4*)(lB)     = pb.q[0];
        *(uint4*)(lB + 8) = pb.q[1];
        __syncthreads();

        short8 af[4], bf[4];
#pragma unroll
        for (int m = 0; m < 4; ++m)
            af[m] = *(const short8*)&As[wr * 64 + m * 16 + lrow][lgrp * 8];
#pragma unroll
        for (int n = 0; n < 4; ++n)
            bf[n] = *(const short8*)&Bs[wc * 64 + n * 16 + lrow][lgrp * 8];
#pragma unroll
        for (int m = 0; m < 4; ++m)
#pragma unroll
            for (int n = 0; n < 4; ++n)
                acc[m][n] = __builtin_amdgcn_mfma_f32_16x16x32_bf16(af[m], bf[n], acc[m][n], 0, 0, 0);
    }

    const int b = mt >> 3;
    float vv[4], ps[4];
#pragma unroll
    for (int n = 0; n < 4; ++n) {
        int col = nt * 128 + wc * 64 + n * 16 + lrow;
        vv[n] = v[col];
        ps[n] = proj_s[b * H_ + col];
    }
    float rs[4][4];
#pragma unroll
    for (int m = 0; m < 4; ++m) {
#pragma unroll
        for (int j = 0; j < 4; ++j) {
            float s = 0.0f;
#pragma unroll
            for (int n = 0; n < 4; ++n)
                s = fmaf(tanh_fast(acc[m][n][j] + ps[n]), vv[n], s);
            s += __shfl_xor(s, 1, 64);
            s += __shfl_xor(s, 2, 64);
            s += __shfl_xor(s, 4, 64);
            s += __shfl_xor(s, 8, 64);
            rs[m][j] = s;
        }
    }
    if (lrow == 0) {
#pragma unroll
        for (int m = 0; m < 4; ++m)
#pragma unroll
            for (int j = 0; j < 4; ++j)
                sums[wr * 64 + m * 16 + lgrp * 4 + j][wc] = rs[m][j];
    }
    __syncthreads();
    if (t < 128)
        scores_part[(size_t)nt * M_ + mt * 128 + t] = sums[t][0] + sums[t][1];
}

// ---------------------------------------------------------------------------
// K3: softmax over S per batch row (np N-tile partials)
// ---------------------------------------------------------------------------
__global__ void softmax_kernel(const float* __restrict__ scores_part,
                               const int* __restrict__ mask,
                               float* __restrict__ weights, int np) {
    const int b = blockIdx.x, t = threadIdx.x;
    __shared__ float red[8];
    float sc[4];
#pragma unroll
    for (int i = 0; i < 4; ++i) {
        int s = t + i * 256;
        float x = 0.0f;
        for (int p = 0; p < np; ++p)
            x += scores_part[(size_t)p * M_ + b * S_ + s];
        if (mask[b * S_ + s] == 0) x = -INFINITY;
        sc[i] = x;
    }
    float mx = fmaxf(fmaxf(sc[0], sc[1]), fmaxf(sc[2], sc[3]));
#pragma unroll
    for (int m = 32; m >= 1; m >>= 1) mx = fmaxf(mx, __shfl_xor(mx, m, 64));
    if ((t & 63) == 0) red[t >> 6] = mx;
    __syncthreads();
    mx = fmaxf(fmaxf(red[0], red[1]), fmaxf(red[2], red[3]));

    float e[4]; float sum = 0.0f;
#pragma unroll
    for (int i = 0; i < 4; ++i) { e[i] = __expf(sc[i] - mx); sum += e[i]; }
#pragma unroll
    for (int m = 32; m >= 1; m >>= 1) sum += __shfl_xor(sum, m, 64);
    if ((t & 63) == 0) red[4 + (t >> 6)] = sum;
    __syncthreads();
    sum = red[4] + red[5] + red[6] + red[7];
    float inv = 1.0f / sum;
#pragma unroll
    for (int i = 0; i < 4; ++i)
        weights[b * S_ + t + i * 256] = e[i] * inv;
}

// ---------------------------------------------------------------------------
// K4 fast: context partials reading bf16 enc. grid = 2048 = b(64) x sc(32).
// ---------------------------------------------------------------------------
__global__ void context_part_bf16_kernel(const unsigned short* __restrict__ encb,
                                         const float* __restrict__ weights,
                                         float* __restrict__ ctx_part) {
    const int b = blockIdx.x >> 5;
    const int sc = blockIdx.x & 31;
    const int t = threadIdx.x;   // 0..127
    __shared__ float wv[32];
    if (t < 32) wv[t] = weights[b * S_ + sc * 32 + t];
    __syncthreads();
    const short8* e8 = (const short8*)(encb + (size_t)(b * S_ + sc * 32) * H_) + t;
    float a[8] = {};
#pragma unroll 4
    for (int i = 0; i < 32; ++i) {
        short8 ev = e8[(size_t)i * 128];
        float w = wv[i];
#pragma unroll
        for (int j = 0; j < 8; ++j)
            a[j] = fmaf(w, bf2f((unsigned short)ev[j]), a[j]);
    }
    float* dst = ctx_part + (size_t)sc * M_ + b * H_ + t * 8;
    float4 o0; o0.x = a[0]; o0.y = a[1]; o0.z = a[2]; o0.w = a[3];
    float4 o1; o1.x = a[4]; o1.y = a[5]; o1.z = a[6]; o1.w = a[7];
    *(float4*)dst = o0;
    *(float4*)(dst + 4) = o1;
}

__global__ void context_part_kernel(const float* __restrict__ enc,
                                    const float* __restrict__ weights,
                                    float* __restrict__ ctx_part) {
    const int b = blockIdx.x >> 4;
    const int sc = blockIdx.x & 15;
    const int t = threadIdx.x;
    __shared__ float wv[64];
    if (t < 64) wv[t] = weights[b * S_ + sc * 64 + t];
    __syncthreads();
    const float4* e4 = (const float4*)(enc + (size_t)(b * S_ + sc * 64) * H_) + t;
    float ax = 0.f, ay = 0.f, az = 0.f, aw = 0.f;
#pragma unroll 4
    for (int i = 0; i < 64; ++i) {
        float4 ev = e4[i * 256];
        float wgt = wv[i];
        ax = fmaf(wgt, ev.x, ax);
        ay = fmaf(wgt, ev.y, ay);
        az = fmaf(wgt, ev.z, az);
        aw = fmaf(wgt, ev.w, aw);
    }
    float4 o; o.x = ax; o.y = ay; o.z = az; o.w = aw;
    *((float4*)(ctx_part + (size_t)sc * M_ + b * H_) + t) = o;
}

__global__ void ctx_reduce_kernel(const float* __restrict__ ctx_part,
                                  float* __restrict__ ctx, int np) {
    int idx = blockIdx.x * 256 + threadIdx.x;
    float s = 0.0f;
    for (int p = 0; p < np; ++p) s += ctx_part[(size_t)p * M_ + idx];
    ctx[idx] = s;
}

extern "C" void kernel_launch(void* const* d_in, const int* in_sizes, int n_in,
                              void* d_out, int out_size, void* d_ws, size_t ws_size,
                              hipStream_t stream) {
    const float* dec  = (const float*)d_in[0];   // [B,H]
    const float* enc  = (const float*)d_in[1];   // [B,S,H]
    const int*   mask = (const int*)d_in[2];     // [B,S]
    const float* Ws   = (const float*)d_in[3];   // [H,H]
    const float* Wh   = (const float*)d_in[4];   // [H,H]
    const float* v    = (const float*)d_in[5];   // [H]

    float* out = (float*)d_out;          // [0:65536] context, [65536:131072] weights

    float* proj_s      = (float*)d_ws;                   // 65536 f32
    float* proj_part   = proj_s + M_;                    // 16 * 65536 f32
    float* scores_part = proj_part + 16 * (size_t)M_;    // 8 * 65536 f32
    float* ctx_part    = scores_part + 8 * (size_t)M_;   // 32 * 65536 f32
    unsigned short* encb = (unsigned short*)(ctx_part + 32 * (size_t)M_);  // 64M bf16
    unsigned short* Whb  = encb + (size_t)B_ * S_ * H_;                    // 1M bf16

    const size_t need_small = 4ull * (1 + 16 + 8 + 32) * M_;
    const size_t need_big   = need_small + 2ull * ((size_t)B_ * S_ * H_ + (size_t)H_ * H_);

    proj_s_part_kernel<<<256, 256, 0, stream>>>(dec, Ws, proj_part);
    proj_red_kernel<<<256, 256, 0, stream>>>(proj_part, proj_s);

    if (ws_size >= need_big) {
        cvt_bf16_kernel<<<2048, 256, 0, stream>>>(enc, encb, B_ * S_ * H_ / 8);
        cvt_bf16_kernel<<<512, 256, 0, stream>>>(Wh, Whb, H_ * H_ / 8);
        fused_scores_8p_kernel<<<1024, 512, 0, stream>>>(encb, Whb, proj_s, v, scores_part);
        softmax_kernel<<<64, 256, 0, stream>>>(scores_part, mask, out + M_, 4);
        context_part_bf16_kernel<<<2048, 128, 0, stream>>>(encb, out + M_, ctx_part);
        ctx_reduce_kernel<<<256, 256, 0, stream>>>(ctx_part, out, 32);
    } else {
        fused_scores_kernel<<<4096, 256, 0, stream>>>(enc, Wh, proj_s, v, scores_part);
        softmax_kernel<<<64, 256, 0, stream>>>(scores_part, mask, out + M_, 8);
        context_part_kernel<<<1024, 256, 0, stream>>>(enc, out + M_, ctx_part);
        ctx_reduce_kernel<<<256, 256, 0, stream>>>(ctx_part, out, 16);
    }
}

// Round 5
// 270.081 us; speedup vs baseline: 1.0395x; 1.0395x over previous
//
#include <hip/hip_runtime.h>
#include <hip/hip_bf16.h>

#define B_ 64
#define S_ 1024
#define H_ 1024
#define M_ (B_*S_)   // 65536 rows of the big GEMM

typedef __attribute__((ext_vector_type(8))) short short8;
typedef __attribute__((ext_vector_type(4))) float f32x4;

__device__ __forceinline__ unsigned short f2bf(float f) {
    union { float f; unsigned u; } c; c.f = f;
    unsigned u = c.u;
    unsigned r = (u + 0x7fffu + ((u >> 16) & 1u)) >> 16;  // RTNE, finite inputs
    return (unsigned short)r;
}

__device__ __forceinline__ float bf2f(unsigned short h) {
    union { unsigned u; float f; } c; c.u = ((unsigned)h) << 16;
    return c.f;
}

__device__ __forceinline__ float tanh_fast(float x) {
    float t = __expf(2.0f * x);
    return 1.0f - 2.0f * __builtin_amdgcn_rcpf(t + 1.0f);  // inf-safe
}

// async global->LDS, 16B per lane. LDS dest = wave-uniform base + lane*16.
__device__ __forceinline__ void gll16(const unsigned short* g, unsigned short* l) {
    auto* gp = (const __attribute__((address_space(1))) unsigned short*)(g);
    auto* lp = (__attribute__((address_space(3))) unsigned short*)(l);
    __builtin_amdgcn_global_load_lds(gp, lp, 16, 0, 0);
}

// ---------------------------------------------------------------------------
// K0: f32 -> bf16 conversion (8 elems/thread/iter, 16B stores)
// ---------------------------------------------------------------------------
__global__ void cvt_bf16_kernel(const float* __restrict__ src,
                                unsigned short* __restrict__ dst, int n8) {
    int idx = blockIdx.x * blockDim.x + threadIdx.x;
    int stride = gridDim.x * blockDim.x;
    for (int i = idx; i < n8; i += stride) {
        const float4* s4 = (const float4*)src + (size_t)i * 2;
        float4 a = s4[0], b = s4[1];
        short8 o;
        o[0] = f2bf(a.x); o[1] = f2bf(a.y); o[2] = f2bf(a.z); o[3] = f2bf(a.w);
        o[4] = f2bf(b.x); o[5] = f2bf(b.y); o[6] = f2bf(b.z); o[7] = f2bf(b.w);
        *((short8*)dst + i) = o;
    }
}

// ---------------------------------------------------------------------------
// K1a: proj_s split-K partials. grid = 256 = (kt 16) x (hs 16), 256 thr.
// ---------------------------------------------------------------------------
__global__ void proj_s_part_kernel(const float* __restrict__ dec,
                                   const float* __restrict__ Ws,
                                   float* __restrict__ part) {
    __shared__ float wss[64][68];
    const int kt = blockIdx.x & 15, hs = blockIdx.x >> 4;
    const int k0 = kt * 64, h0 = hs * 64;
    const int t = threadIdx.x;

    {
        const int r = t >> 2, c = (t & 3) * 16;
        const float4* src = (const float4*)(Ws + (size_t)(k0 + r) * H_ + h0 + c);
        float4 v0 = src[0], v1 = src[1], v2 = src[2], v3 = src[3];
        *(float4*)&wss[r][c + 0]  = v0;
        *(float4*)&wss[r][c + 4]  = v1;
        *(float4*)&wss[r][c + 8]  = v2;
        *(float4*)&wss[r][c + 12] = v3;
    }
    const int b = t >> 2, kq = t & 3;
    float4 dreg[16];
    const float4* dsrc = (const float4*)(dec + (size_t)b * H_ + h0);
#pragma unroll
    for (int i = 0; i < 16; ++i) dreg[i] = dsrc[i];
    __syncthreads();

    float acc[16] = {};
#pragma unroll
    for (int h4 = 0; h4 < 16; ++h4) {
        float4 d = dreg[h4];
#pragma unroll
        for (int j = 0; j < 16; ++j) {
            float4 wv = *(const float4*)&wss[kq + 4 * j][h4 * 4];
            acc[j] = fmaf(d.x, wv.x, acc[j]);
            acc[j] = fmaf(d.y, wv.y, acc[j]);
            acc[j] = fmaf(d.z, wv.z, acc[j]);
            acc[j] = fmaf(d.w, wv.w, acc[j]);
        }
    }
#pragma unroll
    for (int j = 0; j < 16; ++j)
        part[(size_t)hs * M_ + b * H_ + k0 + kq + 4 * j] = acc[j];
}

__global__ void proj_red_kernel(const float* __restrict__ part,
                                float* __restrict__ proj_s) {
    int i = blockIdx.x * 256 + threadIdx.x;
    float s = 0.0f;
#pragma unroll
    for (int p = 0; p < 16; ++p) s += part[(size_t)p * M_ + i];
    proj_s[i] = s;
}

// ---------------------------------------------------------------------------
// K2: 256x256 tile, BK=32, 8 waves, 3-buffer LDS rotation (96KB),
// 2-K-tile prefetch depth, per-phase spread staging, counted vmcnt(4),
// 2 phases x 16 MFMA per K-tile, XOR-swizzled LDS, setprio around MFMA.
//
// Staging protocol (race-free): during tile s, phases issue the 4 half-tiles
// of tile s+2 into buf[(s+2)%3] == buf[(s-1)%3] (dead since the boundary
// barrier entering tile s). Boundary: wait vmcnt(4) -> tile s+1 complete
// (its 4 loads were issued 2 K-tiles = ~8 phases earlier), tile s+2's 4
// loads stay in flight.
// ---------------------------------------------------------------------------
__global__ void __launch_bounds__(512)
fused_scores_8p_kernel(const unsigned short* __restrict__ encb,
                       const unsigned short* __restrict__ Whb,
                       const float* __restrict__ proj_s,
                       const float* __restrict__ v,
                       float* __restrict__ scores_part) {
    __shared__ __align__(16) unsigned short Lsh[49152];  // 96KB: 3 buf x (A 16KB + B 16KB)

    // XCD swizzle: 1024 blocks, 8 XCDs -> each XCD gets 128 consecutive
    const int bx0 = blockIdx.x;
    const int bx = (bx0 & 7) * 128 + (bx0 >> 3);
    const int nt = bx & 3;    // 4 N-tiles of 256
    const int mt = bx >> 2;   // 256 M-tiles of 256
    const int t = threadIdx.x;
    const int wid = t >> 6, lane = t & 63;
    const int wr = wid >> 2, wc = wid & 3;       // 2M x 4N wave grid
    const int lrow = lane & 15, lgrp = lane >> 4;

    f32x4 acc[8][4] = {};

    // ---- staging addresses (pre-swizzled global source, linear LDS dest) ----
    const int srow = t >> 2;                            // 0..127
    const int scol = ((t & 3) ^ ((t >> 3) & 3)) * 8;    // swizzled halfword col
    const unsigned short* gA = encb + (size_t)(mt * 256 + srow) * H_ + scol;
    const unsigned short* gB = Whb  + (size_t)(nt * 256 + srow) * H_ + scol;

    // bufb: 0..2 (32KB each); op: 0=A,1=B; h: half (128 rows); kt: K-tile
    #define STAGE(bufb, op, h, kt) \
        gll16(((op) ? gB : gA) + (size_t)(h) * (128 * H_) + (kt) * 32, \
              Lsh + (bufb) * 16384 + (op) * 8192 + (h) * 4096 + wid * 512)

    // ---- fragment read byte offsets within a region (swizzle matches stage) ----
    int aoff[8], boff[4];
#pragma unroll
    for (int m = 0; m < 8; ++m) {
        int row = wr * 128 + m * 16 + lrow;
        aoff[m] = row * 64 + ((lgrp ^ ((row >> 1) & 3)) * 16);
    }
#pragma unroll
    for (int n = 0; n < 4; ++n) {
        int row = wc * 64 + n * 16 + lrow;
        boff[n] = row * 64 + ((lgrp ^ ((row >> 1) & 3)) * 16);
    }

    // ---- prologue: stage tiles 0 and 1 fully; wait tile 0 (4 stay in flight)
    STAGE(0, 0, 0, 0); STAGE(0, 0, 1, 0); STAGE(0, 1, 0, 0); STAGE(0, 1, 1, 0);
    STAGE(1, 0, 0, 1); STAGE(1, 0, 1, 1); STAGE(1, 1, 0, 1); STAGE(1, 1, 1, 1);
    asm volatile("s_waitcnt vmcnt(4)" ::: "memory");
    __builtin_amdgcn_sched_barrier(0);
    __builtin_amdgcn_s_barrier();

    int bc = 0, bn = 2;   // current buffer (s%3), staging buffer ((s+2)%3)
    for (int s = 0; s < 32; ++s) {
        const char* LA = (const char*)Lsh + bc * 32768;
        const char* LB = LA + 16384;
        const bool st = (s < 30);

        // ---- phase 0: m-frags 0-3 x all n ----
        short8 af[4], bfr[4];
#pragma unroll
        for (int m = 0; m < 4; ++m)
            af[m] = *(const short8*)(LA + aoff[m]);
#pragma unroll
        for (int n = 0; n < 4; ++n)
            bfr[n] = *(const short8*)(LB + boff[n]);
        if (st) { STAGE(bn, 0, 0, s + 2); STAGE(bn, 0, 1, s + 2); }
        __builtin_amdgcn_s_barrier();
        __builtin_amdgcn_s_setprio(1);
#pragma unroll
        for (int m = 0; m < 4; ++m)
#pragma unroll
            for (int n = 0; n < 4; ++n)
                acc[m][n] = __builtin_amdgcn_mfma_f32_16x16x32_bf16(af[m], bfr[n], acc[m][n], 0, 0, 0);
        __builtin_amdgcn_s_setprio(0);
        __builtin_amdgcn_s_barrier();

        // ---- phase 1: m-frags 4-7 x all n (B reused in regs) ----
        short8 af2[4];
#pragma unroll
        for (int m = 0; m < 4; ++m)
            af2[m] = *(const short8*)(LA + aoff[4 + m]);
        if (st) { STAGE(bn, 1, 0, s + 2); STAGE(bn, 1, 1, s + 2); }
        __builtin_amdgcn_s_barrier();
        __builtin_amdgcn_s_setprio(1);
#pragma unroll
        for (int m = 0; m < 4; ++m)
#pragma unroll
            for (int n = 0; n < 4; ++n)
                acc[4 + m][n] = __builtin_amdgcn_mfma_f32_16x16x32_bf16(af2[m], bfr[n], acc[4 + m][n], 0, 0, 0);
        __builtin_amdgcn_s_setprio(0);
        __builtin_amdgcn_s_barrier();

        // ---- boundary: tile s+1 must be complete; s+2's 4 loads stay in flight
        if (s <= 29) { asm volatile("s_waitcnt vmcnt(4)" ::: "memory"); }
        else         { asm volatile("s_waitcnt vmcnt(0)" ::: "memory"); }
        __builtin_amdgcn_sched_barrier(0);
        __builtin_amdgcn_s_barrier();
        bc = (bc == 2) ? 0 : bc + 1;
        bn = (bn == 2) ? 0 : bn + 1;
    }
    #undef STAGE

    // ---- epilogue: tanh(acc + proj_s) . v, reduce over cols ----
    const int b = mt >> 2;   // 4 M-tiles per batch row (256 | 1024)
    float vv[4], ps[4];
#pragma unroll
    for (int n = 0; n < 4; ++n) {
        int col = nt * 256 + wc * 64 + n * 16 + lrow;
        vv[n] = v[col];
        ps[n] = proj_s[b * H_ + col];
    }
    float* sums = (float*)Lsh;   // reuse: [256 rows][4 wc] f32 = 4KB
#pragma unroll
    for (int m = 0; m < 8; ++m) {
#pragma unroll
        for (int j = 0; j < 4; ++j) {
            float s = 0.0f;
#pragma unroll
            for (int n = 0; n < 4; ++n)
                s = fmaf(tanh_fast(acc[m][n][j] + ps[n]), vv[n], s);
            s += __shfl_xor(s, 1, 64);
            s += __shfl_xor(s, 2, 64);
            s += __shfl_xor(s, 4, 64);
            s += __shfl_xor(s, 8, 64);
            if (lrow == 0)
                sums[(wr * 128 + m * 16 + lgrp * 4 + j) * 4 + wc] = s;
        }
    }
    __syncthreads();
    if (t < 256) {
        float r = sums[t * 4 + 0] + sums[t * 4 + 1] + sums[t * 4 + 2] + sums[t * 4 + 3];
        scores_part[(size_t)nt * M_ + mt * 256 + t] = r;
    }
}

// ---------------------------------------------------------------------------
// K2 fallback: f32-input version (reg-staged conversion), 128x128, np=8.
// ---------------------------------------------------------------------------
__global__ void fused_scores_kernel(const float* __restrict__ enc,
                                    const float* __restrict__ Wh,
                                    const float* __restrict__ proj_s,
                                    const float* __restrict__ v,
                                    float* __restrict__ scores_part) {
    __shared__ __align__(16) unsigned short As[128][40];
    __shared__ __align__(16) unsigned short Bs[128][40];
    __shared__ float sums[128][2];

    const int bx = blockIdx.x;
    const int nt = bx & 7;
    const int mt = bx >> 3;
    const int t = threadIdx.x;
    const int w = t >> 6, lane = t & 63;
    const int wr = w >> 1, wc = w & 1;
    const int lrow = lane & 15, lgrp = lane >> 4;

    f32x4 acc[4][4] = {};

    const int srow = t >> 1;
    const int shalf = t & 1;
    const float* gA = enc + (size_t)(mt * 128 + srow) * H_ + shalf * 16;
    const float* gB = Wh  + (size_t)(nt * 128 + srow) * H_ + shalf * 16;
    unsigned short* lA = &As[srow][shalf * 16];
    unsigned short* lB = &Bs[srow][shalf * 16];

    for (int kt = 0; kt < H_ / 32; ++kt) {
        __syncthreads();
        const float4* a4 = (const float4*)(gA + kt * 32);
        const float4* b4 = (const float4*)(gB + kt * 32);
        union { unsigned short us[16]; uint4 q[2]; } pa, pb;
#pragma unroll
        for (int i = 0; i < 4; ++i) {
            float4 av = a4[i];
            float4 bv = b4[i];
            pa.us[i*4+0] = f2bf(av.x); pa.us[i*4+1] = f2bf(av.y);
            pa.us[i*4+2] = f2bf(av.z); pa.us[i*4+3] = f2bf(av.w);
            pb.us[i*4+0] = f2bf(bv.x); pb.us[i*4+1] = f2bf(bv.y);
            pb.us[i*4+2] = f2bf(bv.z); pb.us[i*4+3] = f2bf(bv.w);
        }
        *(uint4*)(lA)     = pa.q[0];
        *(uint4*)(lA + 8) = pa.q[1];
        *(uint4*)(lB)     = pb.q[0];
        *(uint4*)(lB + 8) = pb.q[1];
        __syncthreads();

        short8 af[4], bf[4];
#pragma unroll
        for (int m = 0; m < 4; ++m)
            af[m] = *(const short8*)&As[wr * 64 + m * 16 + lrow][lgrp * 8];
#pragma unroll
        for (int n = 0; n < 4; ++n)
            bf[n] = *(const short8*)&Bs[wc * 64 + n * 16 + lrow][lgrp * 8];
#pragma unroll
        for (int m = 0; m < 4; ++m)
#pragma unroll
            for (int n = 0; n < 4; ++n)
                acc[m][n] = __builtin_amdgcn_mfma_f32_16x16x32_bf16(af[m], bf[n], acc[m][n], 0, 0, 0);
    }

    const int b = mt >> 3;
    float vv[4], ps[4];
#pragma unroll
    for (int n = 0; n < 4; ++n) {
        int col = nt * 128 + wc * 64 + n * 16 + lrow;
        vv[n] = v[col];
        ps[n] = proj_s[b * H_ + col];
    }
    float rs[4][4];
#pragma unroll
    for (int m = 0; m < 4; ++m) {
#pragma unroll
        for (int j = 0; j < 4; ++j) {
            float s = 0.0f;
#pragma unroll
            for (int n = 0; n < 4; ++n)
                s = fmaf(tanh_fast(acc[m][n][j] + ps[n]), vv[n], s);
            s += __shfl_xor(s, 1, 64);
            s += __shfl_xor(s, 2, 64);
            s += __shfl_xor(s, 4, 64);
            s += __shfl_xor(s, 8, 64);
            rs[m][j] = s;
        }
    }
    if (lrow == 0) {
#pragma unroll
        for (int m = 0; m < 4; ++m)
#pragma unroll
            for (int j = 0; j < 4; ++j)
                sums[wr * 64 + m * 16 + lgrp * 4 + j][wc] = rs[m][j];
    }
    __syncthreads();
    if (t < 128)
        scores_part[(size_t)nt * M_ + mt * 128 + t] = sums[t][0] + sums[t][1];
}

// ---------------------------------------------------------------------------
// K3: softmax over S per batch row (np N-tile partials)
// ---------------------------------------------------------------------------
__global__ void softmax_kernel(const float* __restrict__ scores_part,
                               const int* __restrict__ mask,
                               float* __restrict__ weights, int np) {
    const int b = blockIdx.x, t = threadIdx.x;
    __shared__ float red[8];
    float sc[4];
#pragma unroll
    for (int i = 0; i < 4; ++i) {
        int s = t + i * 256;
        float x = 0.0f;
        for (int p = 0; p < np; ++p)
            x += scores_part[(size_t)p * M_ + b * S_ + s];
        if (mask[b * S_ + s] == 0) x = -INFINITY;
        sc[i] = x;
    }
    float mx = fmaxf(fmaxf(sc[0], sc[1]), fmaxf(sc[2], sc[3]));
#pragma unroll
    for (int m = 32; m >= 1; m >>= 1) mx = fmaxf(mx, __shfl_xor(mx, m, 64));
    if ((t & 63) == 0) red[t >> 6] = mx;
    __syncthreads();
    mx = fmaxf(fmaxf(red[0], red[1]), fmaxf(red[2], red[3]));

    float e[4]; float sum = 0.0f;
#pragma unroll
    for (int i = 0; i < 4; ++i) { e[i] = __expf(sc[i] - mx); sum += e[i]; }
#pragma unroll
    for (int m = 32; m >= 1; m >>= 1) sum += __shfl_xor(sum, m, 64);
    if ((t & 63) == 0) red[4 + (t >> 6)] = sum;
    __syncthreads();
    sum = red[4] + red[5] + red[6] + red[7];
    float inv = 1.0f / sum;
#pragma unroll
    for (int i = 0; i < 4; ++i)
        weights[b * S_ + t + i * 256] = e[i] * inv;
}

// ---------------------------------------------------------------------------
// K4 fast: context partials reading bf16 enc. grid = 2048 = b(64) x sc(32).
// ---------------------------------------------------------------------------
__global__ void context_part_bf16_kernel(const unsigned short* __restrict__ encb,
                                         const float* __restrict__ weights,
                                         float* __restrict__ ctx_part) {
    const int b = blockIdx.x >> 5;
    const int sc = blockIdx.x & 31;
    const int t = threadIdx.x;   // 0..127
    __shared__ float wv[32];
    if (t < 32) wv[t] = weights[b * S_ + sc * 32 + t];
    __syncthreads();
    const short8* e8 = (const short8*)(encb + (size_t)(b * S_ + sc * 32) * H_) + t;
    float a[8] = {};
#pragma unroll 4
    for (int i = 0; i < 32; ++i) {
        short8 ev = e8[(size_t)i * 128];
        float w = wv[i];
#pragma unroll
        for (int j = 0; j < 8; ++j)
            a[j] = fmaf(w, bf2f((unsigned short)ev[j]), a[j]);
    }
    float* dst = ctx_part + (size_t)sc * M_ + b * H_ + t * 8;
    float4 o0; o0.x = a[0]; o0.y = a[1]; o0.z = a[2]; o0.w = a[3];
    float4 o1; o1.x = a[4]; o1.y = a[5]; o1.z = a[6]; o1.w = a[7];
    *(float4*)dst = o0;
    *(float4*)(dst + 4) = o1;
}

__global__ void context_part_kernel(const float* __restrict__ enc,
                                    const float* __restrict__ weights,
                                    float* __restrict__ ctx_part) {
    const int b = blockIdx.x >> 4;
    const int sc = blockIdx.x & 15;
    const int t = threadIdx.x;
    __shared__ float wv[64];
    if (t < 64) wv[t] = weights[b * S_ + sc * 64 + t];
    __syncthreads();
    const float4* e4 = (const float4*)(enc + (size_t)(b * S_ + sc * 64) * H_) + t;
    float ax = 0.f, ay = 0.f, az = 0.f, aw = 0.f;
#pragma unroll 4
    for (int i = 0; i < 64; ++i) {
        float4 ev = e4[i * 256];
        float wgt = wv[i];
        ax = fmaf(wgt, ev.x, ax);
        ay = fmaf(wgt, ev.y, ay);
        az = fmaf(wgt, ev.z, az);
        aw = fmaf(wgt, ev.w, aw);
    }
    float4 o; o.x = ax; o.y = ay; o.z = az; o.w = aw;
    *((float4*)(ctx_part + (size_t)sc * M_ + b * H_) + t) = o;
}

__global__ void ctx_reduce_kernel(const float* __restrict__ ctx_part,
                                  float* __restrict__ ctx, int np) {
    int idx = blockIdx.x * 256 + threadIdx.x;
    float s = 0.0f;
    for (int p = 0; p < np; ++p) s += ctx_part[(size_t)p * M_ + idx];
    ctx[idx] = s;
}

extern "C" void kernel_launch(void* const* d_in, const int* in_sizes, int n_in,
                              void* d_out, int out_size, void* d_ws, size_t ws_size,
                              hipStream_t stream) {
    const float* dec  = (const float*)d_in[0];   // [B,H]
    const float* enc  = (const float*)d_in[1];   // [B,S,H]
    const int*   mask = (const int*)d_in[2];     // [B,S]
    const float* Ws   = (const float*)d_in[3];   // [H,H]
    const float* Wh   = (const float*)d_in[4];   // [H,H]
    const float* v    = (const float*)d_in[5];   // [H]

    float* out = (float*)d_out;          // [0:65536] context, [65536:131072] weights

    float* proj_s      = (float*)d_ws;                   // 65536 f32
    float* proj_part   = proj_s + M_;                    // 16 * 65536 f32
    float* scores_part = proj_part + 16 * (size_t)M_;    // 8 * 65536 f32
    float* ctx_part    = scores_part + 8 * (size_t)M_;   // 32 * 65536 f32
    unsigned short* encb = (unsigned short*)(ctx_part + 32 * (size_t)M_);  // 64M bf16
    unsigned short* Whb  = encb + (size_t)B_ * S_ * H_;                    // 1M bf16

    const size_t need_small = 4ull * (1 + 16 + 8 + 32) * M_;
    const size_t need_big   = need_small + 2ull * ((size_t)B_ * S_ * H_ + (size_t)H_ * H_);

    proj_s_part_kernel<<<256, 256, 0, stream>>>(dec, Ws, proj_part);
    proj_red_kernel<<<256, 256, 0, stream>>>(proj_part, proj_s);

    if (ws_size >= need_big) {
        cvt_bf16_kernel<<<2048, 256, 0, stream>>>(enc, encb, B_ * S_ * H_ / 8);
        cvt_bf16_kernel<<<512, 256, 0, stream>>>(Wh, Whb, H_ * H_ / 8);
        fused_scores_8p_kernel<<<1024, 512, 0, stream>>>(encb, Whb, proj_s, v, scores_part);
        softmax_kernel<<<64, 256, 0, stream>>>(scores_part, mask, out + M_, 4);
        context_part_bf16_kernel<<<2048, 128, 0, stream>>>(encb, out + M_, ctx_part);
        ctx_reduce_kernel<<<256, 256, 0, stream>>>(ctx_part, out, 32);
    } else {
        fused_scores_kernel<<<4096, 256, 0, stream>>>(enc, Wh, proj_s, v, scores_part);
        softmax_kernel<<<64, 256, 0, stream>>>(scores_part, mask, out + M_, 8);
        context_part_kernel<<<1024, 256, 0, stream>>>(enc, out + M_, ctx_part);
        ctx_reduce_kernel<<<256, 256, 0, stream>>>(ctx_part, out, 16);
    }
}

// Round 7
// 261.040 us; speedup vs baseline: 1.0755x; 1.0346x over previous
//
#include <hip/hip_runtime.h>
#include <hip/hip_bf16.h>

#define B_ 64
#define S_ 1024
#define H_ 1024
#define M_ (B_*S_)   // 65536 rows of the big GEMM

typedef __attribute__((ext_vector_type(8))) short short8;
typedef __attribute__((ext_vector_type(4))) float f32x4;

__device__ __forceinline__ unsigned short f2bf(float f) {
    union { float f; unsigned u; } c; c.f = f;
    unsigned u = c.u;
    unsigned r = (u + 0x7fffu + ((u >> 16) & 1u)) >> 16;  // RTNE, finite inputs
    return (unsigned short)r;
}

__device__ __forceinline__ float bf2f(unsigned short h) {
    union { unsigned u; float f; } c; c.u = ((unsigned)h) << 16;
    return c.f;
}

__device__ __forceinline__ float tanh_fast(float x) {
    float t = __expf(2.0f * x);
    return 1.0f - 2.0f * __builtin_amdgcn_rcpf(t + 1.0f);  // inf-safe
}

// async global->LDS, 16B per lane. LDS dest = wave-uniform base + lane*16.
__device__ __forceinline__ void gll16(const unsigned short* g, unsigned short* l) {
    auto* gp = (const __attribute__((address_space(1))) unsigned short*)(g);
    auto* lp = (__attribute__((address_space(3))) unsigned short*)(l);
    __builtin_amdgcn_global_load_lds(gp, lp, 16, 0, 0);
}

// ---------------------------------------------------------------------------
// K0: f32 -> bf16 conversion (8 elems/thread/iter, 16B stores)
// ---------------------------------------------------------------------------
__global__ void cvt_bf16_kernel(const float* __restrict__ src,
                                unsigned short* __restrict__ dst, int n8) {
    int idx = blockIdx.x * blockDim.x + threadIdx.x;
    int stride = gridDim.x * blockDim.x;
    for (int i = idx; i < n8; i += stride) {
        const float4* s4 = (const float4*)src + (size_t)i * 2;
        float4 a = s4[0], b = s4[1];
        short8 o;
        o[0] = f2bf(a.x); o[1] = f2bf(a.y); o[2] = f2bf(a.z); o[3] = f2bf(a.w);
        o[4] = f2bf(b.x); o[5] = f2bf(b.y); o[6] = f2bf(b.z); o[7] = f2bf(b.w);
        *((short8*)dst + i) = o;
    }
}

// ---------------------------------------------------------------------------
// K1a: proj_s split-K partials. grid = 256 = (kt 16) x (hs 16), 256 thr.
// ---------------------------------------------------------------------------
__global__ void proj_s_part_kernel(const float* __restrict__ dec,
                                   const float* __restrict__ Ws,
                                   float* __restrict__ part) {
    __shared__ float wss[64][68];
    const int kt = blockIdx.x & 15, hs = blockIdx.x >> 4;
    const int k0 = kt * 64, h0 = hs * 64;
    const int t = threadIdx.x;

    {
        const int r = t >> 2, c = (t & 3) * 16;
        const float4* src = (const float4*)(Ws + (size_t)(k0 + r) * H_ + h0 + c);
        float4 v0 = src[0], v1 = src[1], v2 = src[2], v3 = src[3];
        *(float4*)&wss[r][c + 0]  = v0;
        *(float4*)&wss[r][c + 4]  = v1;
        *(float4*)&wss[r][c + 8]  = v2;
        *(float4*)&wss[r][c + 12] = v3;
    }
    const int b = t >> 2, kq = t & 3;
    float4 dreg[16];
    const float4* dsrc = (const float4*)(dec + (size_t)b * H_ + h0);
#pragma unroll
    for (int i = 0; i < 16; ++i) dreg[i] = dsrc[i];
    __syncthreads();

    float acc[16] = {};
#pragma unroll
    for (int h4 = 0; h4 < 16; ++h4) {
        float4 d = dreg[h4];
#pragma unroll
        for (int j = 0; j < 16; ++j) {
            float4 wv = *(const float4*)&wss[kq + 4 * j][h4 * 4];
            acc[j] = fmaf(d.x, wv.x, acc[j]);
            acc[j] = fmaf(d.y, wv.y, acc[j]);
            acc[j] = fmaf(d.z, wv.z, acc[j]);
            acc[j] = fmaf(d.w, wv.w, acc[j]);
        }
    }
#pragma unroll
    for (int j = 0; j < 16; ++j)
        part[(size_t)hs * M_ + b * H_ + k0 + kq + 4 * j] = acc[j];
}

__global__ void proj_red_kernel(const float* __restrict__ part,
                                float* __restrict__ proj_s) {
    int i = blockIdx.x * 256 + threadIdx.x;
    float s = 0.0f;
#pragma unroll
    for (int p = 0; p < 16; ++p) s += part[(size_t)p * M_ + i];
    proj_s[i] = s;
}

// ---------------------------------------------------------------------------
// K2: 256x256 tile, BK=64, 8 waves (2Mx4N), 2x64KB LDS dbuf,
// 4 phases x 16 MFMA per K-tile, counted vmcnt(6)/vmcnt(2) with 3-phase lead,
// granule-XOR swizzled LDS (128B rows), setprio around MFMA. Fused tanh+v-dot.
//
// Load stream per K-tile s+1 (issued during tile s): ph1: B-q0..3, A-q0, A-q2
// (6 loads); ph2: A-q1, A-q3 (2 loads). Waits: end-ph1: vmcnt(6) -> A-q1,q3
// of tile s landed (issued ph2(s-1), 3 phases earlier); boundary: vmcnt(2) ->
// the 6 of tile s+1 landed (issued ph1(s), 3 phases earlier).
// LAST TILE (st==false): nothing new issued in ph1, so outstanding==2 and
// vmcnt(6) would be a NO-OP while ph2 still reads those 2 loads' data ->
// must drain with vmcnt(0) there (this was the R5 race).
// ---------------------------------------------------------------------------
__global__ void __launch_bounds__(512)
fused_scores_k64_kernel(const unsigned short* __restrict__ encb,
                        const unsigned short* __restrict__ Whb,
                        const float* __restrict__ proj_s,
                        const float* __restrict__ v,
                        float* __restrict__ scores_part) {
    __shared__ __align__(16) unsigned short Lsh[65536];  // 128KB: 2 x (A 32KB + B 32KB)

    // XCD swizzle: 1024 blocks, 8 XCDs -> each XCD gets 128 consecutive
    const int bx0 = blockIdx.x;
    const int bx = (bx0 & 7) * 128 + (bx0 >> 3);
    const int nt = bx & 3;    // 4 N-tiles of 256
    const int mt = bx >> 2;   // 256 M-tiles of 256
    const int t = threadIdx.x;
    const int wid = t >> 6, lane = t & 63;
    const int wr = wid >> 2, wc = wid & 3;       // 2M x 4N wave grid
    const int lrow = lane & 15, lgrp = lane >> 4;

    f32x4 acc[8][4] = {};

    // staging: gload g covers rows g*64..+63, one K-tile's 64 cols (128B rows).
    const int srow = t >> 3;                 // 0..63
    const int sgran = (t & 7) ^ (srow & 7);
    const unsigned short* gA = encb + (size_t)(mt * 256 + srow) * H_ + sgran * 8;
    const unsigned short* gB = Whb  + (size_t)(nt * 256 + srow) * H_ + sgran * 8;

    // bb: buffer 0/1; op: 0=A,1=B; g: row-quarter 0..3; kt: K-tile
#define STG(bb, op, g, kt) \
    gll16(((op) ? gB : gA) + (size_t)(g) * 64 * H_ + (kt) * 64, \
          Lsh + (bb) * 32768 + (op) * 16384 + (g) * 4096 + wid * 512)

    // fragment halfword offsets (kh0); kh1 = offset ^ 32 (granule bit 2)
    int aoff[8], boff[4];
#pragma unroll
    for (int m = 0; m < 8; ++m) {
        int row = wr * 128 + m * 16 + lrow;
        aoff[m] = row * 64 + (lgrp ^ (row & 7)) * 8;
    }
#pragma unroll
    for (int n = 0; n < 4; ++n) {
        int row = wc * 64 + n * 16 + lrow;
        boff[n] = 16384 + row * 64 + (lgrp ^ (row & 7)) * 8;
    }

    // ---- prologue: stage tile 0 fully into buf0 (one-time full drain) ----
    STG(0,1,0,0); STG(0,1,1,0); STG(0,1,2,0); STG(0,1,3,0);
    STG(0,0,0,0); STG(0,0,1,0); STG(0,0,2,0); STG(0,0,3,0);
    asm volatile("s_waitcnt vmcnt(0)" ::: "memory");
    __builtin_amdgcn_sched_barrier(0);
    __builtin_amdgcn_s_barrier();

    int buf = 0;
    for (int s = 0; s < 16; ++s) {
        const int hb = buf * 32768;
        const int sb = buf ^ 1;
        const bool st = (s < 15);
        short8 a0[4], a1[4], b0[4], b1[4];

        // ---- phase 1: A m0-3 @kh0 + B n0-3 @kh0; stage 6 of tile s+1 ----
#pragma unroll
        for (int m = 0; m < 4; ++m) a0[m] = *(const short8*)&Lsh[hb + aoff[m]];
#pragma unroll
        for (int n = 0; n < 4; ++n) b0[n] = *(const short8*)&Lsh[hb + boff[n]];
        if (st) { STG(sb,1,0,s+1); STG(sb,1,1,s+1); STG(sb,1,2,s+1); STG(sb,1,3,s+1);
                  STG(sb,0,0,s+1); STG(sb,0,2,s+1); }
        __builtin_amdgcn_s_barrier();
        __builtin_amdgcn_s_setprio(1);
#pragma unroll
        for (int m = 0; m < 4; ++m)
#pragma unroll
            for (int n = 0; n < 4; ++n)
                acc[m][n] = __builtin_amdgcn_mfma_f32_16x16x32_bf16(a0[m], b0[n], acc[m][n], 0, 0, 0);
        __builtin_amdgcn_s_setprio(0);
        if (st) { asm volatile("s_waitcnt vmcnt(6)" ::: "memory"); }   // A-q1,q3 of tile s landed
        else    { asm volatile("s_waitcnt vmcnt(0)" ::: "memory"); }   // last tile: drain (R5 race fix)
        __builtin_amdgcn_sched_barrier(0);
        __builtin_amdgcn_s_barrier();

        // ---- phase 2: A m4-7 @kh0 (B reg-reused); stage 2 of tile s+1 ----
#pragma unroll
        for (int m = 0; m < 4; ++m) a1[m] = *(const short8*)&Lsh[hb + aoff[4 + m]];
        if (st) { STG(sb,0,1,s+1); STG(sb,0,3,s+1); }
        __builtin_amdgcn_s_barrier();
        __builtin_amdgcn_s_setprio(1);
#pragma unroll
        for (int m = 0; m < 4; ++m)
#pragma unroll
            for (int n = 0; n < 4; ++n)
                acc[4 + m][n] = __builtin_amdgcn_mfma_f32_16x16x32_bf16(a1[m], b0[n], acc[4 + m][n], 0, 0, 0);
        __builtin_amdgcn_s_setprio(0);
        __builtin_amdgcn_s_barrier();

        // ---- phase 3: A m0-3 @kh1 + B n0-3 @kh1 ----
#pragma unroll
        for (int m = 0; m < 4; ++m) a0[m] = *(const short8*)&Lsh[hb + (aoff[m] ^ 32)];
#pragma unroll
        for (int n = 0; n < 4; ++n) b1[n] = *(const short8*)&Lsh[hb + (boff[n] ^ 32)];
        __builtin_amdgcn_s_barrier();
        __builtin_amdgcn_s_setprio(1);
#pragma unroll
        for (int m = 0; m < 4; ++m)
#pragma unroll
            for (int n = 0; n < 4; ++n)
                acc[m][n] = __builtin_amdgcn_mfma_f32_16x16x32_bf16(a0[m], b1[n], acc[m][n], 0, 0, 0);
        __builtin_amdgcn_s_setprio(0);
        __builtin_amdgcn_s_barrier();

        // ---- phase 4: A m4-7 @kh1; boundary counted wait ----
#pragma unroll
        for (int m = 0; m < 4; ++m) a1[m] = *(const short8*)&Lsh[hb + (aoff[4 + m] ^ 32)];
        __builtin_amdgcn_s_barrier();
        __builtin_amdgcn_s_setprio(1);
#pragma unroll
        for (int m = 0; m < 4; ++m)
#pragma unroll
            for (int n = 0; n < 4; ++n)
                acc[4 + m][n] = __builtin_amdgcn_mfma_f32_16x16x32_bf16(a1[m], b1[n], acc[4 + m][n], 0, 0, 0);
        __builtin_amdgcn_s_setprio(0);
        if (st) { asm volatile("s_waitcnt vmcnt(2)" ::: "memory"); }   // the 6 of tile s+1 landed
        else    { asm volatile("s_waitcnt vmcnt(0)" ::: "memory"); }
        __builtin_amdgcn_sched_barrier(0);
        __builtin_amdgcn_s_barrier();
        buf ^= 1;
    }
#undef STG

    // ---- epilogue: tanh(acc + proj_s) . v, reduce over cols ----
    const int b = mt >> 2;   // 4 M-tiles per batch row (256 | 1024)
    float vv[4], ps[4];
#pragma unroll
    for (int n = 0; n < 4; ++n) {
        int col = nt * 256 + wc * 64 + n * 16 + lrow;
        vv[n] = v[col];
        ps[n] = proj_s[b * H_ + col];
    }
    float* sums = (float*)Lsh;   // reuse: [256 rows][4 wc] f32 = 4KB
#pragma unroll
    for (int m = 0; m < 8; ++m) {
#pragma unroll
        for (int j = 0; j < 4; ++j) {
            float s = 0.0f;
#pragma unroll
            for (int n = 0; n < 4; ++n)
                s = fmaf(tanh_fast(acc[m][n][j] + ps[n]), vv[n], s);
            s += __shfl_xor(s, 1, 64);
            s += __shfl_xor(s, 2, 64);
            s += __shfl_xor(s, 4, 64);
            s += __shfl_xor(s, 8, 64);
            if (lrow == 0)
                sums[(wr * 128 + m * 16 + lgrp * 4 + j) * 4 + wc] = s;
        }
    }
    __syncthreads();
    if (t < 256) {
        float r = sums[t * 4 + 0] + sums[t * 4 + 1] + sums[t * 4 + 2] + sums[t * 4 + 3];
        scores_part[(size_t)nt * M_ + mt * 256 + t] = r;
    }
}

// ---------------------------------------------------------------------------
// K2 fallback: f32-input version (reg-staged conversion), 128x128, np=8.
// ---------------------------------------------------------------------------
__global__ void fused_scores_kernel(const float* __restrict__ enc,
                                    const float* __restrict__ Wh,
                                    const float* __restrict__ proj_s,
                                    const float* __restrict__ v,
                                    float* __restrict__ scores_part) {
    __shared__ __align__(16) unsigned short As[128][40];
    __shared__ __align__(16) unsigned short Bs[128][40];
    __shared__ float sums[128][2];

    const int bx = blockIdx.x;
    const int nt = bx & 7;
    const int mt = bx >> 3;
    const int t = threadIdx.x;
    const int w = t >> 6, lane = t & 63;
    const int wr = w >> 1, wc = w & 1;
    const int lrow = lane & 15, lgrp = lane >> 4;

    f32x4 acc[4][4] = {};

    const int srow = t >> 1;
    const int shalf = t & 1;
    const float* gA = enc + (size_t)(mt * 128 + srow) * H_ + shalf * 16;
    const float* gB = Wh  + (size_t)(nt * 128 + srow) * H_ + shalf * 16;
    unsigned short* lA = &As[srow][shalf * 16];
    unsigned short* lB = &Bs[srow][shalf * 16];

    for (int kt = 0; kt < H_ / 32; ++kt) {
        __syncthreads();
        const float4* a4 = (const float4*)(gA + kt * 32);
        const float4* b4 = (const float4*)(gB + kt * 32);
        union { unsigned short us[16]; uint4 q[2]; } pa, pb;
#pragma unroll
        for (int i = 0; i < 4; ++i) {
            float4 av = a4[i];
            float4 bv = b4[i];
            pa.us[i*4+0] = f2bf(av.x); pa.us[i*4+1] = f2bf(av.y);
            pa.us[i*4+2] = f2bf(av.z); pa.us[i*4+3] = f2bf(av.w);
            pb.us[i*4+0] = f2bf(bv.x); pb.us[i*4+1] = f2bf(bv.y);
            pb.us[i*4+2] = f2bf(bv.z); pb.us[i*4+3] = f2bf(bv.w);
        }
        *(uint4*)(lA)     = pa.q[0];
        *(uint4*)(lA + 8) = pa.q[1];
        *(uint4*)(lB)     = pb.q[0];
        *(uint4*)(lB + 8) = pb.q[1];
        __syncthreads();

        short8 af[4], bf[4];
#pragma unroll
        for (int m = 0; m < 4; ++m)
            af[m] = *(const short8*)&As[wr * 64 + m * 16 + lrow][lgrp * 8];
#pragma unroll
        for (int n = 0; n < 4; ++n)
            bf[n] = *(const short8*)&Bs[wc * 64 + n * 16 + lrow][lgrp * 8];
#pragma unroll
        for (int m = 0; m < 4; ++m)
#pragma unroll
            for (int n = 0; n < 4; ++n)
                acc[m][n] = __builtin_amdgcn_mfma_f32_16x16x32_bf16(af[m], bf[n], acc[m][n], 0, 0, 0);
    }

    const int b = mt >> 3;
    float vv[4], ps[4];
#pragma unroll
    for (int n = 0; n < 4; ++n) {
        int col = nt * 128 + wc * 64 + n * 16 + lrow;
        vv[n] = v[col];
        ps[n] = proj_s[b * H_ + col];
    }
    float rs[4][4];
#pragma unroll
    for (int m = 0; m < 4; ++m) {
#pragma unroll
        for (int j = 0; j < 4; ++j) {
            float s = 0.0f;
#pragma unroll
            for (int n = 0; n < 4; ++n)
                s = fmaf(tanh_fast(acc[m][n][j] + ps[n]), vv[n], s);
            s += __shfl_xor(s, 1, 64);
            s += __shfl_xor(s, 2, 64);
            s += __shfl_xor(s, 4, 64);
            s += __shfl_xor(s, 8, 64);
            rs[m][j] = s;
        }
    }
    if (lrow == 0) {
#pragma unroll
        for (int m = 0; m < 4; ++m)
#pragma unroll
            for (int j = 0; j < 4; ++j)
                sums[wr * 64 + m * 16 + lgrp * 4 + j][wc] = rs[m][j];
    }
    __syncthreads();
    if (t < 128)
        scores_part[(size_t)nt * M_ + mt * 128 + t] = sums[t][0] + sums[t][1];
}

// ---------------------------------------------------------------------------
// K3: softmax over S per batch row (np N-tile partials)
// ---------------------------------------------------------------------------
__global__ void softmax_kernel(const float* __restrict__ scores_part,
                               const int* __restrict__ mask,
                               float* __restrict__ weights, int np) {
    const int b = blockIdx.x, t = threadIdx.x;
    __shared__ float red[8];
    float sc[4];
#pragma unroll
    for (int i = 0; i < 4; ++i) {
        int s = t + i * 256;
        float x = 0.0f;
        for (int p = 0; p < np; ++p)
            x += scores_part[(size_t)p * M_ + b * S_ + s];
        if (mask[b * S_ + s] == 0) x = -INFINITY;
        sc[i] = x;
    }
    float mx = fmaxf(fmaxf(sc[0], sc[1]), fmaxf(sc[2], sc[3]));
#pragma unroll
    for (int m = 32; m >= 1; m >>= 1) mx = fmaxf(mx, __shfl_xor(mx, m, 64));
    if ((t & 63) == 0) red[t >> 6] = mx;
    __syncthreads();
    mx = fmaxf(fmaxf(red[0], red[1]), fmaxf(red[2], red[3]));

    float e[4]; float sum = 0.0f;
#pragma unroll
    for (int i = 0; i < 4; ++i) { e[i] = __expf(sc[i] - mx); sum += e[i]; }
#pragma unroll
    for (int m = 32; m >= 1; m >>= 1) sum += __shfl_xor(sum, m, 64);
    if ((t & 63) == 0) red[4 + (t >> 6)] = sum;
    __syncthreads();
    sum = red[4] + red[5] + red[6] + red[7];
    float inv = 1.0f / sum;
#pragma unroll
    for (int i = 0; i < 4; ++i)
        weights[b * S_ + t + i * 256] = e[i] * inv;
}

// ---------------------------------------------------------------------------
// K4 fast: context partials reading bf16 enc. grid = 2048 = b(64) x sc(32).
// ---------------------------------------------------------------------------
__global__ void context_part_bf16_kernel(const unsigned short* __restrict__ encb,
                                         const float* __restrict__ weights,
                                         float* __restrict__ ctx_part) {
    const int b = blockIdx.x >> 5;
    const int sc = blockIdx.x & 31;
    const int t = threadIdx.x;   // 0..127
    __shared__ float wv[32];
    if (t < 32) wv[t] = weights[b * S_ + sc * 32 + t];
    __syncthreads();
    const short8* e8 = (const short8*)(encb + (size_t)(b * S_ + sc * 32) * H_) + t;
    float a[8] = {};
#pragma unroll 4
    for (int i = 0; i < 32; ++i) {
        short8 ev = e8[(size_t)i * 128];
        float w = wv[i];
#pragma unroll
        for (int j = 0; j < 8; ++j)
            a[j] = fmaf(w, bf2f((unsigned short)ev[j]), a[j]);
    }
    float* dst = ctx_part + (size_t)sc * M_ + b * H_ + t * 8;
    float4 o0; o0.x = a[0]; o0.y = a[1]; o0.z = a[2]; o0.w = a[3];
    float4 o1; o1.x = a[4]; o1.y = a[5]; o1.z = a[6]; o1.w = a[7];
    *(float4*)dst = o0;
    *(float4*)(dst + 4) = o1;
}

__global__ void context_part_kernel(const float* __restrict__ enc,
                                    const float* __restrict__ weights,
                                    float* __restrict__ ctx_part) {
    const int b = blockIdx.x >> 4;
    const int sc = blockIdx.x & 15;
    const int t = threadIdx.x;
    __shared__ float wv[64];
    if (t < 64) wv[t] = weights[b * S_ + sc * 64 + t];
    __syncthreads();
    const float4* e4 = (const float4*)(enc + (size_t)(b * S_ + sc * 64) * H_) + t;
    float ax = 0.f, ay = 0.f, az = 0.f, aw = 0.f;
#pragma unroll 4
    for (int i = 0; i < 64; ++i) {
        float4 ev = e4[i * 256];
        float wgt = wv[i];
        ax = fmaf(wgt, ev.x, ax);
        ay = fmaf(wgt, ev.y, ay);
        az = fmaf(wgt, ev.z, az);
        aw = fmaf(wgt, ev.w, aw);
    }
    float4 o; o.x = ax; o.y = ay; o.z = az; o.w = aw;
    *((float4*)(ctx_part + (size_t)sc * M_ + b * H_) + t) = o;
}

__global__ void ctx_reduce_kernel(const float* __restrict__ ctx_part,
                                  float* __restrict__ ctx, int np) {
    int idx = blockIdx.x * 256 + threadIdx.x;
    float s = 0.0f;
    for (int p = 0; p < np; ++p) s += ctx_part[(size_t)p * M_ + idx];
    ctx[idx] = s;
}

extern "C" void kernel_launch(void* const* d_in, const int* in_sizes, int n_in,
                              void* d_out, int out_size, void* d_ws, size_t ws_size,
                              hipStream_t stream) {
    const float* dec  = (const float*)d_in[0];   // [B,H]
    const float* enc  = (const float*)d_in[1];   // [B,S,H]
    const int*   mask = (const int*)d_in[2];     // [B,S]
    const float* Ws   = (const float*)d_in[3];   // [H,H]
    const float* Wh   = (const float*)d_in[4];   // [H,H]
    const float* v    = (const float*)d_in[5];   // [H]

    float* out = (float*)d_out;          // [0:65536] context, [65536:131072] weights

    float* proj_s      = (float*)d_ws;                   // 65536 f32
    float* proj_part   = proj_s + M_;                    // 16 * 65536 f32
    float* scores_part = proj_part + 16 * (size_t)M_;    // 8 * 65536 f32
    float* ctx_part    = scores_part + 8 * (size_t)M_;   // 32 * 65536 f32
    unsigned short* encb = (unsigned short*)(ctx_part + 32 * (size_t)M_);  // 64M bf16
    unsigned short* Whb  = encb + (size_t)B_ * S_ * H_;                    // 1M bf16

    const size_t need_small = 4ull * (1 + 16 + 8 + 32) * M_;
    const size_t need_big   = need_small + 2ull * ((size_t)B_ * S_ * H_ + (size_t)H_ * H_);

    proj_s_part_kernel<<<256, 256, 0, stream>>>(dec, Ws, proj_part);
    proj_red_kernel<<<256, 256, 0, stream>>>(proj_part, proj_s);

    if (ws_size >= need_big) {
        cvt_bf16_kernel<<<2048, 256, 0, stream>>>(enc, encb, B_ * S_ * H_ / 8);
        cvt_bf16_kernel<<<512, 256, 0, stream>>>(Wh, Whb, H_ * H_ / 8);
        fused_scores_k64_kernel<<<1024, 512, 0, stream>>>(encb, Whb, proj_s, v, scores_part);
        softmax_kernel<<<64, 256, 0, stream>>>(scores_part, mask, out + M_, 4);
        context_part_bf16_kernel<<<2048, 128, 0, stream>>>(encb, out + M_, ctx_part);
        ctx_reduce_kernel<<<256, 256, 0, stream>>>(ctx_part, out, 32);
    } else {
        fused_scores_kernel<<<4096, 256, 0, stream>>>(enc, Wh, proj_s, v, scores_part);
        softmax_kernel<<<64, 256, 0, stream>>>(scores_part, mask, out + M_, 8);
        context_part_kernel<<<1024, 256, 0, stream>>>(enc, out + M_, ctx_part);
        ctx_reduce_kernel<<<256, 256, 0, stream>>>(ctx_part, out, 16);
    }
}

// Round 8
// 259.650 us; speedup vs baseline: 1.0813x; 1.0054x over previous
//
#include <hip/hip_runtime.h>
#include <hip/hip_bf16.h>

#define B_ 64
#define S_ 1024
#define H_ 1024
#define M_ (B_*S_)   // 65536 rows of the big GEMM

typedef __attribute__((ext_vector_type(8))) short short8;
typedef __attribute__((ext_vector_type(4))) float f32x4;

__device__ __forceinline__ unsigned short f2bf(float f) {
    union { float f; unsigned u; } c; c.f = f;
    unsigned u = c.u;
    unsigned r = (u + 0x7fffu + ((u >> 16) & 1u)) >> 16;  // RTNE, finite inputs
    return (unsigned short)r;
}

__device__ __forceinline__ float bf2f(unsigned short h) {
    union { unsigned u; float f; } c; c.u = ((unsigned)h) << 16;
    return c.f;
}

__device__ __forceinline__ float tanh_fast(float x) {
    float t = __expf(2.0f * x);
    return 1.0f - 2.0f * __builtin_amdgcn_rcpf(t + 1.0f);  // inf-safe
}

// async global->LDS, 16B per lane. LDS dest = wave-uniform base + lane*16.
__device__ __forceinline__ void gll16(const unsigned short* g, unsigned short* l) {
    auto* gp = (const __attribute__((address_space(1))) unsigned short*)(g);
    auto* lp = (__attribute__((address_space(3))) unsigned short*)(l);
    __builtin_amdgcn_global_load_lds(gp, lp, 16, 0, 0);
}

// ---------------------------------------------------------------------------
// K0: f32 -> bf16 conversion (8 elems/thread/iter, 16B stores)
// ---------------------------------------------------------------------------
__global__ void cvt_bf16_kernel(const float* __restrict__ src,
                                unsigned short* __restrict__ dst, int n8) {
    int idx = blockIdx.x * blockDim.x + threadIdx.x;
    int stride = gridDim.x * blockDim.x;
    for (int i = idx; i < n8; i += stride) {
        const float4* s4 = (const float4*)src + (size_t)i * 2;
        float4 a = s4[0], b = s4[1];
        short8 o;
        o[0] = f2bf(a.x); o[1] = f2bf(a.y); o[2] = f2bf(a.z); o[3] = f2bf(a.w);
        o[4] = f2bf(b.x); o[5] = f2bf(b.y); o[6] = f2bf(b.z); o[7] = f2bf(b.w);
        *((short8*)dst + i) = o;
    }
}

// ---------------------------------------------------------------------------
// K1a: proj_s split-K partials. grid = 256 = (kt 16) x (hs 16), 256 thr.
// ---------------------------------------------------------------------------
__global__ void proj_s_part_kernel(const float* __restrict__ dec,
                                   const float* __restrict__ Ws,
                                   float* __restrict__ part) {
    __shared__ float wss[64][68];
    const int kt = blockIdx.x & 15, hs = blockIdx.x >> 4;
    const int k0 = kt * 64, h0 = hs * 64;
    const int t = threadIdx.x;

    {
        const int r = t >> 2, c = (t & 3) * 16;
        const float4* src = (const float4*)(Ws + (size_t)(k0 + r) * H_ + h0 + c);
        float4 v0 = src[0], v1 = src[1], v2 = src[2], v3 = src[3];
        *(float4*)&wss[r][c + 0]  = v0;
        *(float4*)&wss[r][c + 4]  = v1;
        *(float4*)&wss[r][c + 8]  = v2;
        *(float4*)&wss[r][c + 12] = v3;
    }
    const int b = t >> 2, kq = t & 3;
    float4 dreg[16];
    const float4* dsrc = (const float4*)(dec + (size_t)b * H_ + h0);
#pragma unroll
    for (int i = 0; i < 16; ++i) dreg[i] = dsrc[i];
    __syncthreads();

    float acc[16] = {};
#pragma unroll
    for (int h4 = 0; h4 < 16; ++h4) {
        float4 d = dreg[h4];
#pragma unroll
        for (int j = 0; j < 16; ++j) {
            float4 wv = *(const float4*)&wss[kq + 4 * j][h4 * 4];
            acc[j] = fmaf(d.x, wv.x, acc[j]);
            acc[j] = fmaf(d.y, wv.y, acc[j]);
            acc[j] = fmaf(d.z, wv.z, acc[j]);
            acc[j] = fmaf(d.w, wv.w, acc[j]);
        }
    }
#pragma unroll
    for (int j = 0; j < 16; ++j)
        part[(size_t)hs * M_ + b * H_ + k0 + kq + 4 * j] = acc[j];
}

__global__ void proj_red_kernel(const float* __restrict__ part,
                                float* __restrict__ proj_s) {
    int i = blockIdx.x * 256 + threadIdx.x;
    float s = 0.0f;
#pragma unroll
    for (int p = 0; p < 16; ++p) s += part[(size_t)p * M_ + i];
    proj_s[i] = s;
}

// ---------------------------------------------------------------------------
// K2: 256x256 tile, BK=64, 8 waves (2Mx4N), 2x64KB LDS dbuf.
// BARRIER-MINIMAL tile body: 4 straight-line phases {ds_read || stage-issue ||
// MFMA}, only 2 {counted vmcnt + s_barrier} sync points per K-tile.
// Compiler is free to hoist next-phase ds_reads under current MFMAs (no
// intra-tile barriers); counted vmcnt keeps prefetch in flight (never 0
// mid-loop). granule-XOR swizzled LDS (verified conflict-free in R6).
//
// Stage stream for tile s+1 during tile s (earliest-needed-first):
//   ph0: B0,B1   ph1: B2,B3   ph2: Aq0,Aq2   ph3: Aq1,Aq3
// Consumption in tile s+1: ph0 needs {B0..B3, Aq0, Aq2} (first 6 issued);
// ph1 needs {Aq1, Aq3} (last 2).
// Waits (steady state, outstanding traced per-wave):
//   mid-tile (after ph0): outstanding = 2 old (Aq1,q3 of s) + 2 new -> vmcnt(2)
//     retires the old pair needed by ph1.  Last tile: vmcnt(0) (R5 lesson).
//   boundary (after ph3): outstanding = 8 -> vmcnt(2) retires the 6 needed by
//     ph0(s+1), keeps Aq1,q3(s+1) in flight.
// ---------------------------------------------------------------------------
__global__ void __launch_bounds__(512)
fused_scores_p4_kernel(const unsigned short* __restrict__ encb,
                       const unsigned short* __restrict__ Whb,
                       const float* __restrict__ proj_s,
                       const float* __restrict__ v,
                       float* __restrict__ scores_part) {
    __shared__ __align__(16) unsigned short Lsh[65536];  // 128KB: 2 x (A 32KB + B 32KB)

    // XCD swizzle: 1024 blocks, 8 XCDs -> each XCD gets 128 consecutive
    const int bx0 = blockIdx.x;
    const int bx = (bx0 & 7) * 128 + (bx0 >> 3);
    const int nt = bx & 3;    // 4 N-tiles of 256
    const int mt = bx >> 2;   // 256 M-tiles of 256
    const int t = threadIdx.x;
    const int wid = t >> 6, lane = t & 63;
    const int wr = wid >> 2, wc = wid & 3;       // 2M x 4N wave grid
    const int lrow = lane & 15, lgrp = lane >> 4;

    f32x4 acc[8][4] = {};

    // staging: gload g covers rows g*64..+63, one K-tile's 64 cols (128B rows).
    const int srow = t >> 3;                 // 0..63
    const int sgran = (t & 7) ^ (srow & 7);  // pre-swizzled source granule
    const unsigned short* gA = encb + (size_t)(mt * 256 + srow) * H_ + sgran * 8;
    const unsigned short* gB = Whb  + (size_t)(nt * 256 + srow) * H_ + sgran * 8;

    // bb: buffer 0/1; op: 0=A,1=B; g: row-quarter 0..3; kt: K-tile
#define STG(bb, op, g, kt) \
    gll16(((op) ? gB : gA) + (size_t)(g) * 64 * H_ + (kt) * 64, \
          Lsh + (bb) * 32768 + (op) * 16384 + (g) * 4096 + wid * 512)

    // fragment halfword offsets (k-half 0); k-half 1 = offset ^ 32
    int aoff[8], boff[4];
#pragma unroll
    for (int m = 0; m < 8; ++m) {
        int row = wr * 128 + m * 16 + lrow;
        aoff[m] = row * 64 + (lgrp ^ (row & 7)) * 8;
    }
#pragma unroll
    for (int n = 0; n < 4; ++n) {
        int row = wc * 64 + n * 16 + lrow;
        boff[n] = 16384 + row * 64 + (lgrp ^ (row & 7)) * 8;
    }

    // ---- prologue: stage tile 0 fully into buf0 (one-time full drain) ----
    STG(0,1,0,0); STG(0,1,1,0); STG(0,1,2,0); STG(0,1,3,0);
    STG(0,0,0,0); STG(0,0,1,0); STG(0,0,2,0); STG(0,0,3,0);
    asm volatile("s_waitcnt vmcnt(0)" ::: "memory");
    __builtin_amdgcn_sched_barrier(0);
    __builtin_amdgcn_s_barrier();

    int buf = 0;
    for (int s = 0; s < 16; ++s) {
        const int hb = buf * 32768;
        const int sb = buf ^ 1;
        const bool st = (s < 15);
        short8 a0[4], a1[4], bk0[4], bk1[4];

        // ---- ph0: B@k0 + A m0-3 @k0 ; stage B0,B1 ; MFMA quadrant ----
#pragma unroll
        for (int n = 0; n < 4; ++n) bk0[n] = *(const short8*)&Lsh[hb + boff[n]];
#pragma unroll
        for (int m = 0; m < 4; ++m) a0[m] = *(const short8*)&Lsh[hb + aoff[m]];
        if (st) { STG(sb,1,0,s+1); STG(sb,1,1,s+1); }
        __builtin_amdgcn_s_setprio(1);
#pragma unroll
        for (int m = 0; m < 4; ++m)
#pragma unroll
            for (int n = 0; n < 4; ++n)
                acc[m][n] = __builtin_amdgcn_mfma_f32_16x16x32_bf16(a0[m], bk0[n], acc[m][n], 0, 0, 0);
        __builtin_amdgcn_s_setprio(0);

        // ---- mid-tile sync: retire Aq1,Aq3 of THIS tile before ph1 reads ----
        if (st) { asm volatile("s_waitcnt vmcnt(2)" ::: "memory"); }
        else    { asm volatile("s_waitcnt vmcnt(0)" ::: "memory"); }
        __builtin_amdgcn_sched_barrier(0);
        __builtin_amdgcn_s_barrier();

        // ---- ph1: A m4-7 @k0 + B@k1 ; stage B2,B3 ; MFMA ----
#pragma unroll
        for (int m = 0; m < 4; ++m) a1[m] = *(const short8*)&Lsh[hb + aoff[4 + m]];
#pragma unroll
        for (int n = 0; n < 4; ++n) bk1[n] = *(const short8*)&Lsh[hb + (boff[n] ^ 32)];
        if (st) { STG(sb,1,2,s+1); STG(sb,1,3,s+1); }
        __builtin_amdgcn_s_setprio(1);
#pragma unroll
        for (int m = 0; m < 4; ++m)
#pragma unroll
            for (int n = 0; n < 4; ++n)
                acc[4 + m][n] = __builtin_amdgcn_mfma_f32_16x16x32_bf16(a1[m], bk0[n], acc[4 + m][n], 0, 0, 0);
        __builtin_amdgcn_s_setprio(0);

        // ---- ph2: A m0-3 @k1 ; stage Aq0,Aq2 ; MFMA (B@k1 in regs) ----
#pragma unroll
        for (int m = 0; m < 4; ++m) a0[m] = *(const short8*)&Lsh[hb + (aoff[m] ^ 32)];
        if (st) { STG(sb,0,0,s+1); STG(sb,0,2,s+1); }
        __builtin_amdgcn_s_setprio(1);
#pragma unroll
        for (int m = 0; m < 4; ++m)
#pragma unroll
            for (int n = 0; n < 4; ++n)
                acc[m][n] = __builtin_amdgcn_mfma_f32_16x16x32_bf16(a0[m], bk1[n], acc[m][n], 0, 0, 0);
        __builtin_amdgcn_s_setprio(0);

        // ---- ph3: A m4-7 @k1 ; stage Aq1,Aq3 ; MFMA ----
#pragma unroll
        for (int m = 0; m < 4; ++m) a1[m] = *(const short8*)&Lsh[hb + (aoff[4 + m] ^ 32)];
        if (st) { STG(sb,0,1,s+1); STG(sb,0,3,s+1); }
        __builtin_amdgcn_s_setprio(1);
#pragma unroll
        for (int m = 0; m < 4; ++m)
#pragma unroll
            for (int n = 0; n < 4; ++n)
                acc[4 + m][n] = __builtin_amdgcn_mfma_f32_16x16x32_bf16(a1[m], bk1[n], acc[4 + m][n], 0, 0, 0);
        __builtin_amdgcn_s_setprio(0);

        // ---- boundary: retire the 6 loads ph0(s+1) needs; keep 2 in flight ----
        if (st) { asm volatile("s_waitcnt vmcnt(2)" ::: "memory"); }
        __builtin_amdgcn_sched_barrier(0);
        __builtin_amdgcn_s_barrier();
        buf ^= 1;
    }
#undef STG

    // ---- epilogue: tanh(acc + proj_s) . v, reduce over cols ----
    const int b = mt >> 2;   // 4 M-tiles per batch row (256 | 1024)
    float vv[4], ps[4];
#pragma unroll
    for (int n = 0; n < 4; ++n) {
        int col = nt * 256 + wc * 64 + n * 16 + lrow;
        vv[n] = v[col];
        ps[n] = proj_s[b * H_ + col];
    }
    float* sums = (float*)Lsh;   // reuse: [256 rows][4 wc] f32 = 4KB (buf0 A region; last tile read buf1)
#pragma unroll
    for (int m = 0; m < 8; ++m) {
#pragma unroll
        for (int j = 0; j < 4; ++j) {
            float s = 0.0f;
#pragma unroll
            for (int n = 0; n < 4; ++n)
                s = fmaf(tanh_fast(acc[m][n][j] + ps[n]), vv[n], s);
            s += __shfl_xor(s, 1, 64);
            s += __shfl_xor(s, 2, 64);
            s += __shfl_xor(s, 4, 64);
            s += __shfl_xor(s, 8, 64);
            if (lrow == 0)
                sums[(wr * 128 + m * 16 + lgrp * 4 + j) * 4 + wc] = s;
        }
    }
    __syncthreads();
    if (t < 256) {
        float r = sums[t * 4 + 0] + sums[t * 4 + 1] + sums[t * 4 + 2] + sums[t * 4 + 3];
        scores_part[(size_t)nt * M_ + mt * 256 + t] = r;
    }
}

// ---------------------------------------------------------------------------
// K2 fallback: f32-input version (reg-staged conversion), 128x128, np=8.
// ---------------------------------------------------------------------------
__global__ void fused_scores_kernel(const float* __restrict__ enc,
                                    const float* __restrict__ Wh,
                                    const float* __restrict__ proj_s,
                                    const float* __restrict__ v,
                                    float* __restrict__ scores_part) {
    __shared__ __align__(16) unsigned short As[128][40];
    __shared__ __align__(16) unsigned short Bs[128][40];
    __shared__ float sums[128][2];

    const int bx = blockIdx.x;
    const int nt = bx & 7;
    const int mt = bx >> 3;
    const int t = threadIdx.x;
    const int w = t >> 6, lane = t & 63;
    const int wr = w >> 1, wc = w & 1;
    const int lrow = lane & 15, lgrp = lane >> 4;

    f32x4 acc[4][4] = {};

    const int srow = t >> 1;
    const int shalf = t & 1;
    const float* gA = enc + (size_t)(mt * 128 + srow) * H_ + shalf * 16;
    const float* gB = Wh  + (size_t)(nt * 128 + srow) * H_ + shalf * 16;
    unsigned short* lA = &As[srow][shalf * 16];
    unsigned short* lB = &Bs[srow][shalf * 16];

    for (int kt = 0; kt < H_ / 32; ++kt) {
        __syncthreads();
        const float4* a4 = (const float4*)(gA + kt * 32);
        const float4* b4 = (const float4*)(gB + kt * 32);
        union { unsigned short us[16]; uint4 q[2]; } pa, pb;
#pragma unroll
        for (int i = 0; i < 4; ++i) {
            float4 av = a4[i];
            float4 bv = b4[i];
            pa.us[i*4+0] = f2bf(av.x); pa.us[i*4+1] = f2bf(av.y);
            pa.us[i*4+2] = f2bf(av.z); pa.us[i*4+3] = f2bf(av.w);
            pb.us[i*4+0] = f2bf(bv.x); pb.us[i*4+1] = f2bf(bv.y);
            pb.us[i*4+2] = f2bf(bv.z); pb.us[i*4+3] = f2bf(bv.w);
        }
        *(uint4*)(lA)     = pa.q[0];
        *(uint4*)(lA + 8) = pa.q[1];
        *(uint4*)(lB)     = pb.q[0];
        *(uint4*)(lB + 8) = pb.q[1];
        __syncthreads();

        short8 af[4], bf[4];
#pragma unroll
        for (int m = 0; m < 4; ++m)
            af[m] = *(const short8*)&As[wr * 64 + m * 16 + lrow][lgrp * 8];
#pragma unroll
        for (int n = 0; n < 4; ++n)
            bf[n] = *(const short8*)&Bs[wc * 64 + n * 16 + lrow][lgrp * 8];
#pragma unroll
        for (int m = 0; m < 4; ++m)
#pragma unroll
            for (int n = 0; n < 4; ++n)
                acc[m][n] = __builtin_amdgcn_mfma_f32_16x16x32_bf16(af[m], bf[n], acc[m][n], 0, 0, 0);
    }

    const int b = mt >> 3;
    float vv[4], ps[4];
#pragma unroll
    for (int n = 0; n < 4; ++n) {
        int col = nt * 128 + wc * 64 + n * 16 + lrow;
        vv[n] = v[col];
        ps[n] = proj_s[b * H_ + col];
    }
    float rs[4][4];
#pragma unroll
    for (int m = 0; m < 4; ++m) {
#pragma unroll
        for (int j = 0; j < 4; ++j) {
            float s = 0.0f;
#pragma unroll
            for (int n = 0; n < 4; ++n)
                s = fmaf(tanh_fast(acc[m][n][j] + ps[n]), vv[n], s);
            s += __shfl_xor(s, 1, 64);
            s += __shfl_xor(s, 2, 64);
            s += __shfl_xor(s, 4, 64);
            s += __shfl_xor(s, 8, 64);
            rs[m][j] = s;
        }
    }
    if (lrow == 0) {
#pragma unroll
        for (int m = 0; m < 4; ++m)
#pragma unroll
            for (int j = 0; j < 4; ++j)
                sums[wr * 64 + m * 16 + lgrp * 4 + j][wc] = rs[m][j];
    }
    __syncthreads();
    if (t < 128)
        scores_part[(size_t)nt * M_ + mt * 128 + t] = sums[t][0] + sums[t][1];
}

// ---------------------------------------------------------------------------
// K3: softmax over S per batch row (np N-tile partials)
// ---------------------------------------------------------------------------
__global__ void softmax_kernel(const float* __restrict__ scores_part,
                               const int* __restrict__ mask,
                               float* __restrict__ weights, int np) {
    const int b = blockIdx.x, t = threadIdx.x;
    __shared__ float red[8];
    float sc[4];
#pragma unroll
    for (int i = 0; i < 4; ++i) {
        int s = t + i * 256;
        float x = 0.0f;
        for (int p = 0; p < np; ++p)
            x += scores_part[(size_t)p * M_ + b * S_ + s];
        if (mask[b * S_ + s] == 0) x = -INFINITY;
        sc[i] = x;
    }
    float mx = fmaxf(fmaxf(sc[0], sc[1]), fmaxf(sc[2], sc[3]));
#pragma unroll
    for (int m = 32; m >= 1; m >>= 1) mx = fmaxf(mx, __shfl_xor(mx, m, 64));
    if ((t & 63) == 0) red[t >> 6] = mx;
    __syncthreads();
    mx = fmaxf(fmaxf(red[0], red[1]), fmaxf(red[2], red[3]));

    float e[4]; float sum = 0.0f;
#pragma unroll
    for (int i = 0; i < 4; ++i) { e[i] = __expf(sc[i] - mx); sum += e[i]; }
#pragma unroll
    for (int m = 32; m >= 1; m >>= 1) sum += __shfl_xor(sum, m, 64);
    if ((t & 63) == 0) red[4 + (t >> 6)] = sum;
    __syncthreads();
    sum = red[4] + red[5] + red[6] + red[7];
    float inv = 1.0f / sum;
#pragma unroll
    for (int i = 0; i < 4; ++i)
        weights[b * S_ + t + i * 256] = e[i] * inv;
}

// ---------------------------------------------------------------------------
// K4 fast: context partials reading bf16 enc. grid = 2048 = b(64) x sc(32).
// ---------------------------------------------------------------------------
__global__ void context_part_bf16_kernel(const unsigned short* __restrict__ encb,
                                         const float* __restrict__ weights,
                                         float* __restrict__ ctx_part) {
    const int b = blockIdx.x >> 5;
    const int sc = blockIdx.x & 31;
    const int t = threadIdx.x;   // 0..127
    __shared__ float wv[32];
    if (t < 32) wv[t] = weights[b * S_ + sc * 32 + t];
    __syncthreads();
    const short8* e8 = (const short8*)(encb + (size_t)(b * S_ + sc * 32) * H_) + t;
    float a[8] = {};
#pragma unroll 4
    for (int i = 0; i < 32; ++i) {
        short8 ev = e8[(size_t)i * 128];
        float w = wv[i];
#pragma unroll
        for (int j = 0; j < 8; ++j)
            a[j] = fmaf(w, bf2f((unsigned short)ev[j]), a[j]);
    }
    float* dst = ctx_part + (size_t)sc * M_ + b * H_ + t * 8;
    float4 o0; o0.x = a[0]; o0.y = a[1]; o0.z = a[2]; o0.w = a[3];
    float4 o1; o1.x = a[4]; o1.y = a[5]; o1.z = a[6]; o1.w = a[7];
    *(float4*)dst = o0;
    *(float4*)(dst + 4) = o1;
}

__global__ void context_part_kernel(const float* __restrict__ enc,
                                    const float* __restrict__ weights,
                                    float* __restrict__ ctx_part) {
    const int b = blockIdx.x >> 4;
    const int sc = blockIdx.x & 15;
    const int t = threadIdx.x;
    __shared__ float wv[64];
    if (t < 64) wv[t] = weights[b * S_ + sc * 64 + t];
    __syncthreads();
    const float4* e4 = (const float4*)(enc + (size_t)(b * S_ + sc * 64) * H_) + t;
    float ax = 0.f, ay = 0.f, az = 0.f, aw = 0.f;
#pragma unroll 4
    for (int i = 0; i < 64; ++i) {
        float4 ev = e4[i * 256];
        float wgt = wv[i];
        ax = fmaf(wgt, ev.x, ax);
        ay = fmaf(wgt, ev.y, ay);
        az = fmaf(wgt, ev.z, az);
        aw = fmaf(wgt, ev.w, aw);
    }
    float4 o; o.x = ax; o.y = ay; o.z = az; o.w = aw;
    *((float4*)(ctx_part + (size_t)sc * M_ + b * H_) + t) = o;
}

__global__ void ctx_reduce_kernel(const float* __restrict__ ctx_part,
                                  float* __restrict__ ctx, int np) {
    int idx = blockIdx.x * 256 + threadIdx.x;
    float s = 0.0f;
    for (int p = 0; p < np; ++p) s += ctx_part[(size_t)p * M_ + idx];
    ctx[idx] = s;
}

extern "C" void kernel_launch(void* const* d_in, const int* in_sizes, int n_in,
                              void* d_out, int out_size, void* d_ws, size_t ws_size,
                              hipStream_t stream) {
    const float* dec  = (const float*)d_in[0];   // [B,H]
    const float* enc  = (const float*)d_in[1];   // [B,S,H]
    const int*   mask = (const int*)d_in[2];     // [B,S]
    const float* Ws   = (const float*)d_in[3];   // [H,H]
    const float* Wh   = (const float*)d_in[4];   // [H,H]
    const float* v    = (const float*)d_in[5];   // [H]

    float* out = (float*)d_out;          // [0:65536] context, [65536:131072] weights

    float* proj_s      = (float*)d_ws;                   // 65536 f32
    float* proj_part   = proj_s + M_;                    // 16 * 65536 f32
    float* scores_part = proj_part + 16 * (size_t)M_;    // 8 * 65536 f32
    float* ctx_part    = scores_part + 8 * (size_t)M_;   // 32 * 65536 f32
    unsigned short* encb = (unsigned short*)(ctx_part + 32 * (size_t)M_);  // 64M bf16
    unsigned short* Whb  = encb + (size_t)B_ * S_ * H_;                    // 1M bf16

    const size_t need_small = 4ull * (1 + 16 + 8 + 32) * M_;
    const size_t need_big   = need_small + 2ull * ((size_t)B_ * S_ * H_ + (size_t)H_ * H_);

    proj_s_part_kernel<<<256, 256, 0, stream>>>(dec, Ws, proj_part);
    proj_red_kernel<<<256, 256, 0, stream>>>(proj_part, proj_s);

    if (ws_size >= need_big) {
        cvt_bf16_kernel<<<2048, 256, 0, stream>>>(enc, encb, B_ * S_ * H_ / 8);
        cvt_bf16_kernel<<<512, 256, 0, stream>>>(Wh, Whb, H_ * H_ / 8);
        fused_scores_p4_kernel<<<1024, 512, 0, stream>>>(encb, Whb, proj_s, v, scores_part);
        softmax_kernel<<<64, 256, 0, stream>>>(scores_part, mask, out + M_, 4);
        context_part_bf16_kernel<<<2048, 128, 0, stream>>>(encb, out + M_, ctx_part);
        ctx_reduce_kernel<<<256, 256, 0, stream>>>(ctx_part, out, 32);
    } else {
        fused_scores_kernel<<<4096, 256, 0, stream>>>(enc, Wh, proj_s, v, scores_part);
        softmax_kernel<<<64, 256, 0, stream>>>(scores_part, mask, out + M_, 8);
        context_part_kernel<<<1024, 256, 0, stream>>>(enc, out + M_, ctx_part);
        ctx_reduce_kernel<<<256, 256, 0, stream>>>(ctx_part, out, 16);
    }
}